// Round 4
// baseline (392.409 us; speedup 1.0000x reference)
//
#include <hip/hip_runtime.h>
#include <stdint.h>

// ---------------- problem constants ----------------
#define BB 8
#define CC 3
#define HH 128
#define DD 2048
#define FF 8192
#define NCLS 1000
#define MTOK (BB*CC*HH)          // 3072 tokens
#define NW   (FF*DD)             // 16777216 weight elements per matrix
#define INV_NW (1.0f/16777216.0f)

typedef __attribute__((ext_vector_type(4))) int i32x4;
typedef __attribute__((ext_vector_type(16))) int i32x16;
typedef _Float16 f16x8 __attribute__((ext_vector_type(8)));

// ---------------- workspace layout (bytes) ----------------
#define WS_SUMS    0            // 3 floats (finalized by K2)
#define WS_PART    256          // 768 floats: per-block abs-sum partials (3 x 256)
#define WS_POOLED  4096         // 3072 floats (one per token, plain stores)
#define WS_TSUM    16384        // 8192 floats (zeroed by K1, atomicAdd in K2)
#define WS_INVSA   49152        // 3072 floats
#define WS_XQ      61440        // int8 [3072][2048]
#define WS_WGQ     6352896      // int8 [8192][2048]
#define WS_WUQ     23130112     // int8 [8192][2048]
#define WS_H       39907328     // fp16 [3072][8192]
#define WS_NEED    90238976

// 256-thread block reduce; caller manages reuse via `first`
__device__ __forceinline__ float reduce256(float v, float* red, bool first) {
  for (int off = 32; off > 0; off >>= 1) v += __shfl_xor(v, off);
  if (!first) __syncthreads();
  if ((threadIdx.x & 63) == 0) red[threadIdx.x >> 6] = v;
  __syncthreads();
  return (red[0] + red[1]) + (red[2] + red[3]);
}

// ---------------- K1: abssum partials (bx<768) | quant_x (768..3839) | tsum zero (3840) ----------------
__global__ __launch_bounds__(256) void prep_kernel(
    const float* __restrict__ Wg, const float* __restrict__ Wu,
    const float* __restrict__ Wd, const float* __restrict__ x,
    float* __restrict__ part, int8_t* __restrict__ xq,
    float* __restrict__ inv_sa, float* __restrict__ tsum) {
  const int bx = blockIdx.x, t = threadIdx.x;
  if (bx < 768) {
    const int mat = bx >> 8;
    const float* w = (mat == 0) ? Wg : (mat == 1) ? Wu : Wd;
    const float4* w4 = (const float4*)w;
    const unsigned idx = (bx & 255) * 256 + t;     // 0..65535
    float s0 = 0.f, s1 = 0.f, s2 = 0.f, s3 = 0.f;
#pragma unroll 4
    for (int it = 0; it < 64; it += 4) {
      float4 a = w4[idx + (size_t)(it + 0) * 65536];
      float4 b = w4[idx + (size_t)(it + 1) * 65536];
      float4 c = w4[idx + (size_t)(it + 2) * 65536];
      float4 d = w4[idx + (size_t)(it + 3) * 65536];
      s0 += fabsf(a.x) + fabsf(a.y) + fabsf(a.z) + fabsf(a.w);
      s1 += fabsf(b.x) + fabsf(b.y) + fabsf(b.z) + fabsf(b.w);
      s2 += fabsf(c.x) + fabsf(c.y) + fabsf(c.z) + fabsf(c.w);
      s3 += fabsf(d.x) + fabsf(d.y) + fabsf(d.z) + fabsf(d.w);
    }
    __shared__ float red[4];
    float total = reduce256((s0 + s1) + (s2 + s3), red, true);
    if (t == 0) part[bx] = total;
  } else if (bx < 3840) {
    const int tok = bx - 768;
    const float* row = x + (size_t)tok * DD;
    float4 v0 = *(const float4*)(row + t * 4);
    float4 v1 = *(const float4*)(row + 1024 + t * 4);
    float mx = fmaxf(fmaxf(fmaxf(fabsf(v0.x), fabsf(v0.y)), fmaxf(fabsf(v0.z), fabsf(v0.w))),
                     fmaxf(fmaxf(fabsf(v1.x), fabsf(v1.y)), fmaxf(fabsf(v1.z), fabsf(v1.w))));
    for (int off = 32; off > 0; off >>= 1) mx = fmaxf(mx, __shfl_xor(mx, off));
    __shared__ float wm[4];
    if ((t & 63) == 0) wm[t >> 6] = mx;
    __syncthreads();
    float m = fmaxf(fmaxf(wm[0], wm[1]), fmaxf(wm[2], wm[3]));
    float mclip = fmaxf(m, 1e-5f);
    float sa = 127.0f / mclip;
    if (t == 0) inv_sa[tok] = mclip * (1.0f / 127.0f);
    float qv[8] = {v0.x, v0.y, v0.z, v0.w, v1.x, v1.y, v1.z, v1.w};
    unsigned p0 = 0, p1 = 0;
#pragma unroll
    for (int j = 0; j < 4; ++j) {
      int qi = (int)fminf(fmaxf(rintf(qv[j] * sa), -128.f), 127.f);
      p0 |= ((unsigned)(qi & 0xff)) << (8 * j);
    }
#pragma unroll
    for (int j = 0; j < 4; ++j) {
      int qi = (int)fminf(fmaxf(rintf(qv[4 + j] * sa), -128.f), 127.f);
      p1 |= ((unsigned)(qi & 0xff)) << (8 * j);
    }
    *(unsigned*)(xq + (size_t)tok * DD + t * 4) = p0;
    *(unsigned*)(xq + (size_t)tok * DD + 1024 + t * 4) = p1;
  } else {
    float4 z = {0.f, 0.f, 0.f, 0.f};
#pragma unroll
    for (int j = 0; j < 8; ++j)
      *(float4*)(tsum + j * 1024 + t * 4) = z;
  }
}

// ---------------- K2: ternarize Wg/Wu (bx<8192) | Wd colsum (8192..8447) + sums finalize ----------------
__global__ __launch_bounds__(256) void wquant_kernel(
    const float* __restrict__ Wg, const float* __restrict__ Wu,
    const float* __restrict__ Wd, const float* __restrict__ part,
    float* __restrict__ sums, int8_t* __restrict__ wgq,
    int8_t* __restrict__ wuq, float* __restrict__ tsum) {
  const int bx = blockIdx.x, t = threadIdx.x;
  __shared__ float red[4];
  if (bx < 8192) {
    const int mat = bx >> 12;
    const float* w = mat ? Wu : Wg;
    int8_t* wq = mat ? wuq : wgq;
    const float total = reduce256(part[mat * 256 + t], red, true);
    const float scale = 1.0f / fmaxf(total * INV_NW, 1e-5f);
    const unsigned base = (bx & 4095) * 4096;
    float4 v[4];
#pragma unroll
    for (int j = 0; j < 4; ++j)
      v[j] = *(const float4*)(w + base + j * 1024 + t * 4);
#pragma unroll
    for (int j = 0; j < 4; ++j) {
      float vv[4] = {v[j].x, v[j].y, v[j].z, v[j].w};
      unsigned p = 0;
#pragma unroll
      for (int jj = 0; jj < 4; ++jj) {
        int qi = (int)fminf(fmaxf(rintf(vv[jj] * scale), -1.f), 1.f);
        p |= ((unsigned)(qi & 0xff)) << (8 * jj);
      }
      *(unsigned*)(wq + base + j * 1024 + t * 4) = p;
    }
  } else {
    const int idx = bx - 8192;          // 0..255
    const int slab = idx >> 5, colg = idx & 31;
    const float totalWd = reduce256(part[512 + t], red, true);
    const float scale = 1.0f / fmaxf(totalWd * INV_NW, 1e-5f);
    const int col = colg * 256 + t;
    const float* wp = Wd + (size_t)(slab * 256) * FF + col;
    float acc = 0.f;
#pragma unroll 8
    for (int d = 0; d < 256; ++d)
      acc += fminf(fmaxf(rintf(wp[(size_t)d * FF] * scale), -1.f), 1.f);
    atomicAdd(&tsum[col], acc);
    if (idx == 255) {
      const float tg = reduce256(part[t], red, false);
      const float tu = reduce256(part[256 + t], red, false);
      if (t == 0) { sums[0] = tg; sums[1] = tu; sums[2] = totalWd; }
    }
  }
}

// ---------------- K3: fused int8 32x32x32-MFMA GEMM (g and u) + silu*u -> fp16 h ----------------
// Block tile M=128, N=64, BK=128. 4 waves 2x2, wave tile 64x32 (2 m-tiles of 32x32).
// acc = 2 tiles x 16 regs x 2 gemms = 64 AGPR; + ~50 VGPR -> 4 blocks/CU.
__device__ __forceinline__ void gl_lds16(const void* g, void* l) {
  __builtin_amdgcn_global_load_lds((const __attribute__((address_space(1))) void*)g,
                                   (__attribute__((address_space(3))) void*)l, 16, 0, 0);
}

__global__ __launch_bounds__(256, 4) void gemm_gu_kernel(
    const int8_t* __restrict__ Aq,    // [3072][2048]
    const int8_t* __restrict__ Bgq,   // [8192][2048]
    const int8_t* __restrict__ Buq,   // [8192][2048]
    const float* __restrict__ inv_sa, // [3072]
    const float* __restrict__ sums,
    _Float16* __restrict__ Hbuf)      // [3072][8192]
{
  __shared__ int8_t ldsA[128 * 128];  // 16 KB, rows of 128 B = 8 chunks of 16 B
  __shared__ int8_t ldsG[64 * 128];   // 8 KB
  __shared__ int8_t ldsU[64 * 128];   // 8 KB

  const int t = threadIdx.x;
  const int wave = t >> 6, lane = t & 63;
  const int l32 = lane & 31, l5 = lane >> 5;
  const int m0 = blockIdx.x * 128;    // token tile
  const int n0 = blockIdx.y * 64;     // F tile
  const int wm = (wave >> 1) * 64, wn = (wave & 1) * 32;

  i32x16 accg[2], accu[2];
#pragma unroll
  for (int i = 0; i < 2; ++i)
#pragma unroll
    for (int r = 0; r < 16; ++r) { accg[i][r] = 0; accu[i][r] = 0; }

  const int srow = lane >> 3;  // 0..7: row within an 8-row staging call
  const int sp = lane & 7;     // chunk position 0..7

  for (int k0 = 0; k0 < DD; k0 += 128) {
    __syncthreads();
#pragma unroll
    for (int j = 0; j < 4; ++j) {
      const int rl = wave * 32 + j * 8 + srow;
      const int cg = sp ^ (rl & 7);           // XOR swizzle over 8 chunk slots
      gl_lds16(Aq + (size_t)(m0 + rl) * DD + k0 + cg * 16,
               ldsA + (wave * 32 + j * 8) * 128);
    }
#pragma unroll
    for (int j = 0; j < 2; ++j) {
      const int rl = wave * 16 + j * 8 + srow;
      const int cg = sp ^ (rl & 7);
      gl_lds16(Bgq + (size_t)(n0 + rl) * DD + k0 + cg * 16,
               ldsG + (wave * 16 + j * 8) * 128);
      gl_lds16(Buq + (size_t)(n0 + rl) * DD + k0 + cg * 16,
               ldsU + (wave * 16 + j * 8) * 128);
    }
    __syncthreads();

#pragma unroll
    for (int ks = 0; ks < 4; ++ks) {         // K=32 per MFMA, 4 steps over BK=128
      i32x4 af[2], gfv, ufv;
#pragma unroll
      for (int mt = 0; mt < 2; ++mt) {
        const int row = wm + mt * 32 + l32;
        const int p = (ks * 2 + l5) ^ (row & 7);
        af[mt] = *(const i32x4*)(ldsA + row * 128 + p * 16);
      }
      {
        const int row = wn + l32;
        const int p = (ks * 2 + l5) ^ (row & 7);
        gfv = *(const i32x4*)(ldsG + row * 128 + p * 16);
        ufv = *(const i32x4*)(ldsU + row * 128 + p * 16);
      }
#pragma unroll
      for (int mt = 0; mt < 2; ++mt) {
        accg[mt] = __builtin_amdgcn_mfma_i32_32x32x32_i8(af[mt], gfv, accg[mt], 0, 0, 0);
        accu[mt] = __builtin_amdgcn_mfma_i32_32x32x32_i8(af[mt], ufv, accu[mt], 0, 0, 0);
      }
    }
  }

  const float meanWg = fmaxf(sums[0] * INV_NW, 1e-5f);
  const float meanWu = fmaxf(sums[1] * INV_NW, 1e-5f);
  const int coln = n0 + wn + l32;
#pragma unroll
  for (int mt = 0; mt < 2; ++mt) {
#pragma unroll
    for (int r = 0; r < 16; ++r) {
      // 32x32 C/D layout: col=lane&31, row=(reg&3)+8*(reg>>2)+4*(lane>>5)
      const int row = m0 + wm + mt * 32 + (r & 3) + 8 * (r >> 2) + 4 * l5;
      const float isa = inv_sa[row];
      const float g = (float)accg[mt][r] * (isa * meanWg);
      const float u = (float)accu[mt][r] * (isa * meanWu);
      const float sv = g / (1.0f + expf(-g));        // silu
      Hbuf[(size_t)row * FF + coln] = (_Float16)(sv * u);
    }
  }
}

// ---------------- K4: rmsnorm stats + requant + dot(tsum) per token (no atomics) ----------------
__global__ __launch_bounds__(256) void rms_quant_dot_kernel(
    const _Float16* __restrict__ H, const float* __restrict__ lnw,
    const float* __restrict__ tsum, float* __restrict__ pooled) {
  const int tok = blockIdx.x, t = threadIdx.x;
  const _Float16* row = H + (size_t)tok * FF;
  f16x8 hv[4];
  float4 lw[8];
  float ssq = 0.f, mx = 0.f;
#pragma unroll
  for (int i = 0; i < 4; ++i) {
    hv[i] = *(const f16x8*)(row + i * 2048 + t * 8);
    lw[2 * i] = *(const float4*)(lnw + i * 2048 + t * 8);
    lw[2 * i + 1] = *(const float4*)(lnw + i * 2048 + t * 8 + 4);
    const float* lwp = (const float*)&lw[2 * i];
#pragma unroll
    for (int j = 0; j < 8; ++j) {
      float h = (float)hv[i][j];
      ssq += h * h;
      mx = fmaxf(mx, fabsf(h * lwp[j]));
    }
  }
  for (int off = 32; off > 0; off >>= 1) {
    ssq += __shfl_xor(ssq, off);
    mx = fmaxf(mx, __shfl_xor(mx, off));
  }
  __shared__ float rs[4], rm[4], ra[4];
  const int wave = t >> 6, lane = t & 63;
  if (lane == 0) { rs[wave] = ssq; rm[wave] = mx; }
  __syncthreads();
  const float S = (rs[0] + rs[1]) + (rs[2] + rs[3]);
  const float M = fmaxf(fmaxf(rm[0], rm[1]), fmaxf(rm[2], rm[3]));
  const float r = rsqrtf(S * (1.0f / (float)FF) + 1e-6f);
  const float mc = fmaxf(M * r, 1e-5f);     // clip(max|y|, Q_EPS)
  const float as2 = 127.0f / mc;
  float acc = 0.f;
#pragma unroll
  for (int i = 0; i < 4; ++i) {
    float4 t0 = *(const float4*)(tsum + i * 2048 + t * 8);
    float4 t1 = *(const float4*)(tsum + i * 2048 + t * 8 + 4);
    const float* lwp = (const float*)&lw[2 * i];
    const float* tp0 = (const float*)&t0;
    const float* tp1 = (const float*)&t1;
#pragma unroll
    for (int j = 0; j < 8; ++j) {
      float ts = (j < 4) ? tp0[j] : tp1[j - 4];
      float y = (float)hv[i][j] * lwp[j] * r;
      acc += fminf(fmaxf(rintf(y * as2), -128.f), 127.f) * ts;
    }
  }
  for (int off = 32; off > 0; off >>= 1) acc += __shfl_xor(acc, off);
  if (lane == 0) ra[wave] = acc;
  __syncthreads();
  if (t == 0)
    pooled[tok] = ((ra[0] + ra[1]) + (ra[2] + ra[3])) * (mc * (1.0f / 127.0f));
}

// ---------------- K5: classifier (reduces 128 tokens per (b,c) itself) ----------------
__global__ __launch_bounds__(256) void classifier_kernel(
    const float* __restrict__ pooled, const float* __restrict__ sums,
    const float* __restrict__ clsW, const float* __restrict__ clsb,
    float* __restrict__ out) {
  const int b = blockIdx.x, t = threadIdx.x;
  const float meanWd = fmaxf(sums[2] * INV_NW, 1e-5f);
  const float sc = meanWd * (1.0f / (float)(HH * DD));
  __shared__ float ps[3];
#pragma unroll
  for (int c = 0; c < 3; ++c) {
    float s = 0.f;
    if (t < 64) {
      const float* base = pooled + (b * 3 + c) * 128;
      s = base[t] + base[t + 64];
      for (int off = 32; off > 0; off >>= 1) s += __shfl_xor(s, off);
      if (t == 0) ps[c] = s * sc;
    }
    __syncthreads();
  }
  const float p0 = ps[0], p1 = ps[1], p2 = ps[2];
  for (int n = t; n < NCLS; n += 256)
    out[b * NCLS + n] = clsb[n] + p0 * clsW[n * 3 + 0] + p1 * clsW[n * 3 + 1] + p2 * clsW[n * 3 + 2];
}

// ---------------- launch ----------------
extern "C" void kernel_launch(void* const* d_in, const int* in_sizes, int n_in,
                              void* d_out, int out_size, void* d_ws, size_t ws_size,
                              hipStream_t stream) {
  if (n_in < 7 || ws_size < (size_t)WS_NEED) return;
  const float* x = (const float*)d_in[0];
  const float* Wg = (const float*)d_in[1];
  const float* Wu = (const float*)d_in[2];
  const float* Wd = (const float*)d_in[3];
  const float* lnw = (const float*)d_in[4];
  const float* clsW = (const float*)d_in[5];
  const float* clsb = (const float*)d_in[6];
  float* out = (float*)d_out;
  char* ws = (char*)d_ws;
  float* sums = (float*)(ws + WS_SUMS);
  float* part = (float*)(ws + WS_PART);
  float* pooled = (float*)(ws + WS_POOLED);
  float* tsum = (float*)(ws + WS_TSUM);
  float* inv_sa = (float*)(ws + WS_INVSA);
  int8_t* xq = (int8_t*)(ws + WS_XQ);
  int8_t* wgq = (int8_t*)(ws + WS_WGQ);
  int8_t* wuq = (int8_t*)(ws + WS_WUQ);
  _Float16* hbuf = (_Float16*)(ws + WS_H);

  prep_kernel<<<3841, 256, 0, stream>>>(Wg, Wu, Wd, x, part, xq, inv_sa, tsum);
  wquant_kernel<<<8448, 256, 0, stream>>>(Wg, Wu, Wd, part, sums, wgq, wuq, tsum);
  gemm_gu_kernel<<<dim3(24, 128), 256, 0, stream>>>(xq, wgq, wuq, inv_sa, sums, hbuf);
  rms_quant_dot_kernel<<<MTOK, 256, 0, stream>>>(hbuf, lnw, tsum, pooled);
  classifier_kernel<<<BB, 256, 0, stream>>>(pooled, sums, clsW, clsb, out);
  (void)in_sizes; (void)out_size;
}

// Round 5
// 374.752 us; speedup vs baseline: 1.0471x; 1.0471x over previous
//
#include <hip/hip_runtime.h>
#include <stdint.h>

// ---------------- problem constants ----------------
#define BB 8
#define CC 3
#define HH 128
#define DD 2048
#define FF 8192
#define NCLS 1000
#define MTOK (BB*CC*HH)          // 3072 tokens
#define NW   (FF*DD)             // 16777216 weight elements per matrix
#define INV_NW (1.0f/16777216.0f)

typedef __attribute__((ext_vector_type(4))) int i32x4;
typedef _Float16 f16x8 __attribute__((ext_vector_type(8)));

// ---------------- workspace layout (bytes) ----------------
#define WS_SUMS    0            // 3 floats (finalized in K2)
#define WS_PART    256          // 6144 floats: per-block abs-sum partials (3 x 2048)
#define WS_POOLED  24832        // 3072 floats (one per token, plain stores)
#define WS_TSUM    37120        // 8192 floats (zeroed by K1, atomicAdd in K2)
#define WS_INVSA   69888        // 3072 floats
#define WS_XQ      82176        // int8 [3072][2048]
#define WS_WGQ     6373632      // int8 [8192][2048]
#define WS_WUQ     23150848     // int8 [8192][2048]
#define WS_H       39928064     // fp16 [3072][8192]
#define WS_NEED    90259712

// 256-thread block reduce; caller manages LDS reuse via `first`
__device__ __forceinline__ float reduce256(float v, float* red, bool first) {
  for (int off = 32; off > 0; off >>= 1) v += __shfl_xor(v, off);
  if (!first) __syncthreads();
  if ((threadIdx.x & 63) == 0) red[threadIdx.x >> 6] = v;
  __syncthreads();
  return (red[0] + red[1]) + (red[2] + red[3]);
}

// ---------------- K1: abssum partials (bx<6144) | quant_x (6144..9215) | tsum zero (9216) ----
// abssum: 2048 blocks/matrix, each block a contiguous 32KB chunk,
// 8 independent coalesced float4 loads per thread (deep MLP).
__global__ __launch_bounds__(256) void prep_kernel(
    const float* __restrict__ Wg, const float* __restrict__ Wu,
    const float* __restrict__ Wd, const float* __restrict__ x,
    float* __restrict__ part, int8_t* __restrict__ xq,
    float* __restrict__ inv_sa, float* __restrict__ tsum) {
  const int bx = blockIdx.x, t = threadIdx.x;
  if (bx < 6144) {
    const int mat = bx >> 11;
    const float* w = (mat == 0) ? Wg : (mat == 1) ? Wu : Wd;
    const float4* w4 = (const float4*)w + (size_t)(bx & 2047) * 2048;
    float4 v[8];
#pragma unroll
    for (int j = 0; j < 8; ++j) v[j] = w4[j * 256 + t];
    float s = 0.f;
#pragma unroll
    for (int j = 0; j < 8; ++j)
      s += fabsf(v[j].x) + fabsf(v[j].y) + fabsf(v[j].z) + fabsf(v[j].w);
    __shared__ float red[4];
    float total = reduce256(s, red, true);
    if (t == 0) part[bx] = total;
  } else if (bx < 9216) {
    const int tok = bx - 6144;
    const float* row = x + (size_t)tok * DD;
    float4 v0 = *(const float4*)(row + t * 4);
    float4 v1 = *(const float4*)(row + 1024 + t * 4);
    float mx = fmaxf(fmaxf(fmaxf(fabsf(v0.x), fabsf(v0.y)), fmaxf(fabsf(v0.z), fabsf(v0.w))),
                     fmaxf(fmaxf(fabsf(v1.x), fabsf(v1.y)), fmaxf(fabsf(v1.z), fabsf(v1.w))));
    for (int off = 32; off > 0; off >>= 1) mx = fmaxf(mx, __shfl_xor(mx, off));
    __shared__ float wm[4];
    if ((t & 63) == 0) wm[t >> 6] = mx;
    __syncthreads();
    float m = fmaxf(fmaxf(wm[0], wm[1]), fmaxf(wm[2], wm[3]));
    float mclip = fmaxf(m, 1e-5f);
    float sa = 127.0f / mclip;
    if (t == 0) inv_sa[tok] = mclip * (1.0f / 127.0f);
    float qv[8] = {v0.x, v0.y, v0.z, v0.w, v1.x, v1.y, v1.z, v1.w};
    unsigned p0 = 0, p1 = 0;
#pragma unroll
    for (int j = 0; j < 4; ++j) {
      int qi = (int)fminf(fmaxf(rintf(qv[j] * sa), -128.f), 127.f);
      p0 |= ((unsigned)(qi & 0xff)) << (8 * j);
    }
#pragma unroll
    for (int j = 0; j < 4; ++j) {
      int qi = (int)fminf(fmaxf(rintf(qv[4 + j] * sa), -128.f), 127.f);
      p1 |= ((unsigned)(qi & 0xff)) << (8 * j);
    }
    *(unsigned*)(xq + (size_t)tok * DD + t * 4) = p0;
    *(unsigned*)(xq + (size_t)tok * DD + 1024 + t * 4) = p1;
  } else {
    float4 z = {0.f, 0.f, 0.f, 0.f};
#pragma unroll
    for (int j = 0; j < 8; ++j)
      *(float4*)(tsum + j * 1024 + t * 4) = z;
  }
}

// ---------------- K2: ternarize Wg/Wu (bx<4096) | Wd colsum (4096..4607) + sums finalize ----
__global__ __launch_bounds__(256) void wquant_kernel(
    const float* __restrict__ Wg, const float* __restrict__ Wu,
    const float* __restrict__ Wd, const float* __restrict__ part,
    float* __restrict__ sums, int8_t* __restrict__ wgq,
    int8_t* __restrict__ wuq, float* __restrict__ tsum) {
  const int bx = blockIdx.x, t = threadIdx.x;
  __shared__ float red[4];
  if (bx < 4096) {
    const int mat = bx >> 11;
    const float* w = mat ? Wu : Wg;
    int8_t* wq = mat ? wuq : wgq;
    float ps = 0.f;
#pragma unroll
    for (int j = 0; j < 8; ++j) ps += part[mat * 2048 + j * 256 + t];
    const float total = reduce256(ps, red, true);
    const float scale = 1.0f / fmaxf(total * INV_NW, 1e-5f);
    const size_t base = (size_t)(bx & 2047) * 8192;   // floats
    float4 v[8];
#pragma unroll
    for (int j = 0; j < 8; ++j)
      v[j] = *(const float4*)(w + base + j * 1024 + t * 4);
#pragma unroll
    for (int j = 0; j < 8; ++j) {
      float vv[4] = {v[j].x, v[j].y, v[j].z, v[j].w};
      unsigned p = 0;
#pragma unroll
      for (int jj = 0; jj < 4; ++jj) {
        int qi = (int)fminf(fmaxf(rintf(vv[jj] * scale), -1.f), 1.f);
        p |= ((unsigned)(qi & 0xff)) << (8 * jj);
      }
      *(unsigned*)(wq + base + j * 1024 + t * 4) = p;
    }
  } else {
    const int idx = bx - 4096;          // 0..511
    const int slab = idx >> 5, colg = idx & 31;
    float ps = 0.f;
#pragma unroll
    for (int j = 0; j < 8; ++j) ps += part[4096 + j * 256 + t];
    const float totalWd = reduce256(ps, red, true);
    const float scale = 1.0f / fmaxf(totalWd * INV_NW, 1e-5f);
    const int col = colg * 256 + t;
    const float* wp = Wd + (size_t)(slab * 128) * FF + col;
    float acc = 0.f;
#pragma unroll 8
    for (int d = 0; d < 128; ++d)
      acc += fminf(fmaxf(rintf(wp[(size_t)d * FF] * scale), -1.f), 1.f);
    atomicAdd(&tsum[col], acc);
    if (idx == 511) {
      float pg = 0.f, pu = 0.f;
#pragma unroll
      for (int j = 0; j < 8; ++j) { pg += part[j * 256 + t]; pu += part[2048 + j * 256 + t]; }
      const float tg = reduce256(pg, red, false);
      const float tu = reduce256(pu, red, false);
      if (t == 0) { sums[0] = tg; sums[1] = tu; sums[2] = totalWd; }
    }
  }
}

// ---------------- K3: fused int8 16x16x64-MFMA GEMM (g and u) + silu*u -> fp16 h ----------------
// (Round-3 kernel: 113 us, 0 bank conflicts.)
__device__ __forceinline__ void gl_lds16(const void* g, void* l) {
  __builtin_amdgcn_global_load_lds((const __attribute__((address_space(1))) void*)g,
                                   (__attribute__((address_space(3))) void*)l, 16, 0, 0);
}

__global__ __launch_bounds__(256, 3) void gemm_gu_kernel(
    const int8_t* __restrict__ Aq,    // [3072][2048]
    const int8_t* __restrict__ Bgq,   // [8192][2048]
    const int8_t* __restrict__ Buq,   // [8192][2048]
    const float* __restrict__ inv_sa, // [3072]
    const float* __restrict__ sums,
    _Float16* __restrict__ Hbuf)      // [3072][8192]
{
  __shared__ int8_t ldsA[128 * 128];  // 16 KB, rows of 128 B = 8 chunks of 16 B
  __shared__ int8_t ldsG[64 * 128];   // 8 KB
  __shared__ int8_t ldsU[64 * 128];   // 8 KB

  const int t = threadIdx.x;
  const int wave = t >> 6, lane = t & 63;
  const int q = lane >> 4, ln = lane & 15;
  const int m0 = blockIdx.x * 128;    // token tile
  const int n0 = blockIdx.y * 64;     // F tile
  const int wm = (wave >> 1) * 64, wn = (wave & 1) * 32;

  i32x4 accg[4][2], accu[4][2];
#pragma unroll
  for (int i = 0; i < 4; ++i)
#pragma unroll
    for (int j = 0; j < 2; ++j) { accg[i][j] = i32x4{0,0,0,0}; accu[i][j] = i32x4{0,0,0,0}; }

  const int srow = lane >> 3;  // 0..7: row within an 8-row staging call
  const int sp = lane & 7;     // chunk position 0..7

  for (int k0 = 0; k0 < DD; k0 += 128) {
    __syncthreads();
#pragma unroll
    for (int j = 0; j < 4; ++j) {
      const int rl = wave * 32 + j * 8 + srow;
      const int cg = sp ^ (rl & 7);           // XOR swizzle over 8 chunk slots
      gl_lds16(Aq + (size_t)(m0 + rl) * DD + k0 + cg * 16,
               ldsA + (wave * 32 + j * 8) * 128);
    }
#pragma unroll
    for (int j = 0; j < 2; ++j) {
      const int rl = wave * 16 + j * 8 + srow;
      const int cg = sp ^ (rl & 7);
      gl_lds16(Bgq + (size_t)(n0 + rl) * DD + k0 + cg * 16,
               ldsG + (wave * 16 + j * 8) * 128);
      gl_lds16(Buq + (size_t)(n0 + rl) * DD + k0 + cg * 16,
               ldsU + (wave * 16 + j * 8) * 128);
    }
    __syncthreads();

#pragma unroll
    for (int s = 0; s < 2; ++s) {
      i32x4 af[4], gf[2], uf[2];
#pragma unroll
      for (int mt = 0; mt < 4; ++mt) {
        const int row = wm + mt * 16 + ln;
        const int p = (s * 4 + q) ^ (row & 7);
        af[mt] = *(const i32x4*)(ldsA + row * 128 + p * 16);
      }
#pragma unroll
      for (int nt = 0; nt < 2; ++nt) {
        const int row = wn + nt * 16 + ln;
        const int p = (s * 4 + q) ^ (row & 7);
        gf[nt] = *(const i32x4*)(ldsG + row * 128 + p * 16);
        uf[nt] = *(const i32x4*)(ldsU + row * 128 + p * 16);
      }
#pragma unroll
      for (int mt = 0; mt < 4; ++mt)
#pragma unroll
        for (int nt = 0; nt < 2; ++nt) {
          accg[mt][nt] = __builtin_amdgcn_mfma_i32_16x16x64_i8(af[mt], gf[nt], accg[mt][nt], 0, 0, 0);
          accu[mt][nt] = __builtin_amdgcn_mfma_i32_16x16x64_i8(af[mt], uf[nt], accu[mt][nt], 0, 0, 0);
        }
    }
  }

  const float meanWg = fmaxf(sums[0] * INV_NW, 1e-5f);
  const float meanWu = fmaxf(sums[1] * INV_NW, 1e-5f);
#pragma unroll
  for (int mt = 0; mt < 4; ++mt) {
#pragma unroll
    for (int r = 0; r < 4; ++r) {
      const int row = m0 + wm + mt * 16 + q * 4 + r;   // C/D layout: row = quad*4+reg
      const float isa = inv_sa[row];
      const float sg = isa * meanWg, su = isa * meanWu;
      _Float16* hrow = Hbuf + (size_t)row * FF + n0 + wn;
#pragma unroll
      for (int nt = 0; nt < 2; ++nt) {
        const float g = (float)accg[mt][nt][r] * sg;
        const float u = (float)accu[mt][nt][r] * su;
        const float sv = g / (1.0f + expf(-g));        // silu
        hrow[nt * 16 + ln] = (_Float16)(sv * u);       // col = lane&15
      }
    }
  }
}

// ---------------- K4: rmsnorm stats + requant + dot(tsum) per token (no atomics) ----------------
__global__ __launch_bounds__(256) void rms_quant_dot_kernel(
    const _Float16* __restrict__ H, const float* __restrict__ lnw,
    const float* __restrict__ tsum, float* __restrict__ pooled) {
  const int tok = blockIdx.x, t = threadIdx.x;
  const _Float16* row = H + (size_t)tok * FF;
  f16x8 hv[4];
  float4 lw[8];
  float ssq = 0.f, mx = 0.f;
#pragma unroll
  for (int i = 0; i < 4; ++i) {
    hv[i] = *(const f16x8*)(row + i * 2048 + t * 8);
    lw[2 * i] = *(const float4*)(lnw + i * 2048 + t * 8);
    lw[2 * i + 1] = *(const float4*)(lnw + i * 2048 + t * 8 + 4);
    const float* lwp = (const float*)&lw[2 * i];
#pragma unroll
    for (int j = 0; j < 8; ++j) {
      float h = (float)hv[i][j];
      ssq += h * h;
      mx = fmaxf(mx, fabsf(h * lwp[j]));
    }
  }
  for (int off = 32; off > 0; off >>= 1) {
    ssq += __shfl_xor(ssq, off);
    mx = fmaxf(mx, __shfl_xor(mx, off));
  }
  __shared__ float rs[4], rm[4], ra[4];
  const int wave = t >> 6, lane = t & 63;
  if (lane == 0) { rs[wave] = ssq; rm[wave] = mx; }
  __syncthreads();
  const float S = (rs[0] + rs[1]) + (rs[2] + rs[3]);
  const float M = fmaxf(fmaxf(rm[0], rm[1]), fmaxf(rm[2], rm[3]));
  const float r = rsqrtf(S * (1.0f / (float)FF) + 1e-6f);
  const float mc = fmaxf(M * r, 1e-5f);     // clip(max|y|, Q_EPS)
  const float as2 = 127.0f / mc;
  float acc = 0.f;
#pragma unroll
  for (int i = 0; i < 4; ++i) {
    float4 t0 = *(const float4*)(tsum + i * 2048 + t * 8);
    float4 t1 = *(const float4*)(tsum + i * 2048 + t * 8 + 4);
    const float* lwp = (const float*)&lw[2 * i];
    const float* tp0 = (const float*)&t0;
    const float* tp1 = (const float*)&t1;
#pragma unroll
    for (int j = 0; j < 8; ++j) {
      float ts = (j < 4) ? tp0[j] : tp1[j - 4];
      float y = (float)hv[i][j] * lwp[j] * r;
      acc += fminf(fmaxf(rintf(y * as2), -128.f), 127.f) * ts;
    }
  }
  for (int off = 32; off > 0; off >>= 1) acc += __shfl_xor(acc, off);
  if (lane == 0) ra[wave] = acc;
  __syncthreads();
  if (t == 0)
    pooled[tok] = ((ra[0] + ra[1]) + (ra[2] + ra[3])) * (mc * (1.0f / 127.0f));
}

// ---------------- K5: classifier (reduces 128 tokens per (b,c) itself) ----------------
__global__ __launch_bounds__(256) void classifier_kernel(
    const float* __restrict__ pooled, const float* __restrict__ sums,
    const float* __restrict__ clsW, const float* __restrict__ clsb,
    float* __restrict__ out) {
  const int b = blockIdx.x, t = threadIdx.x;
  const float meanWd = fmaxf(sums[2] * INV_NW, 1e-5f);
  const float sc = meanWd * (1.0f / (float)(HH * DD));
  __shared__ float ps[3];
#pragma unroll
  for (int c = 0; c < 3; ++c) {
    float s = 0.f;
    if (t < 64) {
      const float* base = pooled + (b * 3 + c) * 128;
      s = base[t] + base[t + 64];
      for (int off = 32; off > 0; off >>= 1) s += __shfl_xor(s, off);
      if (t == 0) ps[c] = s * sc;
    }
    __syncthreads();
  }
  const float p0 = ps[0], p1 = ps[1], p2 = ps[2];
  for (int n = t; n < NCLS; n += 256)
    out[b * NCLS + n] = clsb[n] + p0 * clsW[n * 3 + 0] + p1 * clsW[n * 3 + 1] + p2 * clsW[n * 3 + 2];
}

// ---------------- launch ----------------
extern "C" void kernel_launch(void* const* d_in, const int* in_sizes, int n_in,
                              void* d_out, int out_size, void* d_ws, size_t ws_size,
                              hipStream_t stream) {
  if (n_in < 7 || ws_size < (size_t)WS_NEED) return;
  const float* x = (const float*)d_in[0];
  const float* Wg = (const float*)d_in[1];
  const float* Wu = (const float*)d_in[2];
  const float* Wd = (const float*)d_in[3];
  const float* lnw = (const float*)d_in[4];
  const float* clsW = (const float*)d_in[5];
  const float* clsb = (const float*)d_in[6];
  float* out = (float*)d_out;
  char* ws = (char*)d_ws;
  float* sums = (float*)(ws + WS_SUMS);
  float* part = (float*)(ws + WS_PART);
  float* pooled = (float*)(ws + WS_POOLED);
  float* tsum = (float*)(ws + WS_TSUM);
  float* inv_sa = (float*)(ws + WS_INVSA);
  int8_t* xq = (int8_t*)(ws + WS_XQ);
  int8_t* wgq = (int8_t*)(ws + WS_WGQ);
  int8_t* wuq = (int8_t*)(ws + WS_WUQ);
  _Float16* hbuf = (_Float16*)(ws + WS_H);

  prep_kernel<<<9217, 256, 0, stream>>>(Wg, Wu, Wd, x, part, xq, inv_sa, tsum);
  wquant_kernel<<<4608, 256, 0, stream>>>(Wg, Wu, Wd, part, sums, wgq, wuq, tsum);
  gemm_gu_kernel<<<dim3(24, 128), 256, 0, stream>>>(xq, wgq, wuq, inv_sa, sums, hbuf);
  rms_quant_dot_kernel<<<MTOK, 256, 0, stream>>>(hbuf, lnw, tsum, pooled);
  classifier_kernel<<<BB, 256, 0, stream>>>(pooled, sums, clsW, clsb, out);
  (void)in_sizes; (void)out_size;
}